// Round 14
// baseline (98.363 us; speedup 1.0000x reference)
//
#include <hip/hip_runtime.h>
#include <cstdint>
#include <cstddef>

#define NB 8
#define NTOK 2048
#define TOKENS (NB * NTOK)   // 16384
#define D 1024
#define E 64
#define CAP 40
#define EC (E * CAP)         // 2560
#define OUT_TENSOR ((size_t)TOKENS * EC)  // 41943040
#define CHUNKS 32            // per batch (k_pos)
#define CHTOK 64             // tokens per chunk (k_pos)

#define TOTAL_F4 20971520ull // (2*OUT_TENSOR)/4

typedef __attribute__((ext_vector_type(8))) short short8v;
typedef __attribute__((ext_vector_type(4))) float f32x4;

__device__ __forceinline__ unsigned short f2bf(float f) {
  unsigned u = __float_as_uint(f);
  unsigned r = (u + 0x7FFFu + ((u >> 16) & 1u)) >> 16;   // RNE
  return (unsigned short)r;
}

// Non-temporal zero store (evict-first, no L2 allocate). Validated +22 us (R11).
__device__ __forceinline__ void nt_zero(float4* p) {
  __builtin_nontemporal_store((f32x4){0.f, 0.f, 0.f, 0.f},
                              reinterpret_cast<f32x4*>(p));
}

// ---------------- Kernel 0: wT[e][k] = bf16(w[k][e]); zero proxyacc ----------------
__global__ __launch_bounds__(256) void k_prep(const float* __restrict__ w,
                                              unsigned short* __restrict__ wT,
                                              float* __restrict__ proxyacc) {
  int gid = blockIdx.x * 256 + threadIdx.x;   // 65536 total
  int e = gid >> 10, k = gid & 1023;
  wT[gid] = f2bf(w[k * E + e]);
  if (blockIdx.x == 0) {
    proxyacc[threadIdx.x] = 0.f;
    proxyacc[threadIdx.x + 256] = 0.f;
  }
}

// ------- Kernel 1: [barrier-free gemm + in-register gate (fused) || ALL nt fill] -------
// Blocks 0..255: verbatim validated R13 gemm+gate (logits never touch memory).
// Blocks 256..1023: nt-fill the ENTIRE 335.5 MB output (grid-stride) — K1's
// gemm side has slack (R13 inference), so the whole fill hides under it and
// K2 is free to fuse pos+scatter with no fill race.
__global__ __launch_bounds__(256, 1) void k_gemmgate_fill(const float* __restrict__ x,
                                                          const unsigned short* __restrict__ wT,
                                                          const float* __restrict__ noise,
                                                          int* __restrict__ i1o, int* __restrict__ i2o,
                                                          float* __restrict__ g1o, float* __restrict__ g2o,
                                                          float* __restrict__ proxyacc,
                                                          float* __restrict__ zpart,
                                                          float* __restrict__ out) {
  const int tid = threadIdx.x;

  if (blockIdx.x >= 256) {
    float4* o4 = reinterpret_cast<float4*>(out);
    const size_t stride = 768 * 256;
    for (size_t q = (size_t)(blockIdx.x - 256) * 256 + tid; q < TOTAL_F4; q += stride)
      nt_zero(&o4[q]);
    return;
  }

  const int m0 = blockIdx.x * 64;
  const int l = tid & 63;
  const int wv = tid >> 6;
  const int h = l >> 4;        // k-subgroup 0..3
  const int r = l & 15;

  const float* xrow = x + (size_t)(m0 + 16 * wv + r) * D;
  const unsigned short* wr0 = wT + (size_t)(r) * D;
  const unsigned short* wr1 = wT + (size_t)(16 + r) * D;
  const unsigned short* wr2 = wT + (size_t)(32 + r) * D;
  const unsigned short* wr3 = wT + (size_t)(48 + r) * D;

  f32x4 acc[4];
#pragma unroll
  for (int f = 0; f < 4; ++f) acc[f] = (f32x4){0.f, 0.f, 0.f, 0.f};

  f32x4 ua[2][2], va[2][2];
  short8v bb[2][2][4];

#define LOAD(BUF, C)                                                   \
  {                                                                    \
    _Pragma("unroll") for (int s = 0; s < 2; ++s) {                    \
      const int k0 = 64 * (C) + 32 * s + 8 * h;                        \
      ua[BUF][s] = *(const f32x4*)(xrow + k0);                         \
      va[BUF][s] = *(const f32x4*)(xrow + k0 + 4);                     \
      bb[BUF][s][0] = *(const short8v*)(wr0 + k0);                     \
      bb[BUF][s][1] = *(const short8v*)(wr1 + k0);                     \
      bb[BUF][s][2] = *(const short8v*)(wr2 + k0);                     \
      bb[BUF][s][3] = *(const short8v*)(wr3 + k0);                     \
    }                                                                  \
  }

  LOAD(0, 0);
#pragma unroll
  for (int c = 0; c < 16; ++c) {
    const int cur = c & 1;              // compile-time under full unroll
    if (c < 15) LOAD((c + 1) & 1, c + 1);
#pragma unroll
    for (int s = 0; s < 2; ++s) {
      f32x4 u = ua[cur][s];
      f32x4 v = va[cur][s];
      short8v av;
      av[0] = (short)f2bf(u.x); av[1] = (short)f2bf(u.y);
      av[2] = (short)f2bf(u.z); av[3] = (short)f2bf(u.w);
      av[4] = (short)f2bf(v.x); av[5] = (short)f2bf(v.y);
      av[6] = (short)f2bf(v.z); av[7] = (short)f2bf(v.w);
#pragma unroll
      for (int f = 0; f < 4; ++f)
        acc[f] = __builtin_amdgcn_mfma_f32_16x16x32_bf16(av, bb[cur][s][f], acc[f], 0, 0, 0);
    }
  }
#undef LOAD

  // ---- fused gate (verbatim validated R7/R13): lane l=16h+r holds
  // acc[f][rr] = logits[token=m0+16wv+4h+rr][expert=16f+r] ----
  const int bslot = (m0 >> 11) * E;
  float pxl0 = 0.f, pxl1 = 0.f, pxl2 = 0.f, pxl3 = 0.f;
  float zw = 0.f;
  int c1a[4], c2a[4];
  float g1a[4], g2a[4];
  bool routea[4];

#pragma unroll
  for (int rr = 0; rr < 4; ++rr) {
    float l0 = acc[0][rr], l1 = acc[1][rr], l2 = acc[2][rr], l3 = acc[3][rr];
    float m = fmaxf(fmaxf(l0, l1), fmaxf(l2, l3));
#pragma unroll
    for (int off = 1; off < 16; off <<= 1) m = fmaxf(m, __shfl_xor(m, off));
    float p0 = expf(l0 - m), p1 = expf(l1 - m), p2 = expf(l2 - m), p3 = expf(l3 - m);
    float s = p0 + p1 + p2 + p3;
#pragma unroll
    for (int off = 1; off < 16; off <<= 1) s += __shfl_xor(s, off);

    float m1 = fmaxf(fmaxf(p0, p1), fmaxf(p2, p3));
#pragma unroll
    for (int off = 1; off < 16; off <<= 1) m1 = fmaxf(m1, __shfl_xor(m1, off));
    int lidx = 999;
    if (p0 == m1) lidx = r;
    if (p1 == m1) lidx = min(lidx, 16 + r);
    if (p2 == m1) lidx = min(lidx, 32 + r);
    if (p3 == m1) lidx = min(lidx, 48 + r);
#pragma unroll
    for (int off = 1; off < 16; off <<= 1) lidx = min(lidx, __shfl_xor(lidx, off));
    int c1 = lidx;

    float q0 = (c1 == r) ? -1.f : p0;
    float q1 = (c1 == 16 + r) ? -1.f : p1;
    float q2 = (c1 == 32 + r) ? -1.f : p2;
    float q3 = (c1 == 48 + r) ? -1.f : p3;
    float m2 = fmaxf(fmaxf(q0, q1), fmaxf(q2, q3));
#pragma unroll
    for (int off = 1; off < 16; off <<= 1) m2 = fmaxf(m2, __shfl_xor(m2, off));
    int lidx2 = 999;
    if (q0 == m2) lidx2 = r;
    if (q1 == m2) lidx2 = min(lidx2, 16 + r);
    if (q2 == m2) lidx2 = min(lidx2, 32 + r);
    if (q3 == m2) lidx2 = min(lidx2, 48 + r);
#pragma unroll
    for (int off = 1; off < 16; off <<= 1) lidx2 = min(lidx2, __shfl_xor(lidx2, off));
    int c2 = lidx2;

    float g1 = m1 / s;
    float g2 = m2 / s;
    float denom = g1 + g2 + 1e-9f;
    float g1n = g1 / denom;
    float g2n = g2 / denom;
    int token = m0 + 16 * wv + 4 * h + rr;
    bool route = noise[token] < (g2n / 0.2f);

    c1a[rr] = c1; c2a[rr] = c2; g1a[rr] = g1n; g2a[rr] = g2n; routea[rr] = route;

    pxl0 += p0 / s; pxl1 += p1 / s; pxl2 += p2 / s; pxl3 += p3 / s;
    float lse = m + logf(s);
    zw += lse * lse;
  }

  if (r == 0) {
#pragma unroll
    for (int rr = 0; rr < 4; ++rr) {
      int token = m0 + 16 * wv + 4 * h + rr;
      i1o[token] = c1a[rr];
      i2o[token] = routea[rr] ? c2a[rr] : -1;
      g1o[token] = g1a[rr];
      g2o[token] = g2a[rr];
    }
  }

  pxl0 += __shfl_xor(pxl0, 16); pxl0 += __shfl_xor(pxl0, 32);
  pxl1 += __shfl_xor(pxl1, 16); pxl1 += __shfl_xor(pxl1, 32);
  pxl2 += __shfl_xor(pxl2, 16); pxl2 += __shfl_xor(pxl2, 32);
  pxl3 += __shfl_xor(pxl3, 16); pxl3 += __shfl_xor(pxl3, 32);
  if (l < 16) {
    atomicAdd(&proxyacc[bslot + r], pxl0);
    atomicAdd(&proxyacc[bslot + 16 + r], pxl1);
    atomicAdd(&proxyacc[bslot + 32 + r], pxl2);
    atomicAdd(&proxyacc[bslot + 48 + r], pxl3);
  }
  zw += __shfl_xor(zw, 16); zw += __shfl_xor(zw, 32);
  if (l == 0) zpart[blockIdx.x * 4 + wv] = zw;
}

// ------------- Kernel 2: pos + DIRECT scatter (fill already complete) -------------
// 8 blocks x 1024 thr, one per batch. Verbatim validated pos logic; instead of
// a tokinfo round-trip + separate scatter kernel, each block writes its own
// tokens' <=2 nonzero combine/dispatch entries directly.
__global__ __launch_bounds__(1024) void k_pos_scatter(const int* __restrict__ i1,
                                                      const int* __restrict__ i2r,
                                                      const float* __restrict__ g1,
                                                      const float* __restrict__ g2,
                                                      int* __restrict__ count1,
                                                      float* __restrict__ out) {
  __shared__ unsigned char pos1c[NTOK];
  __shared__ unsigned char pos2c[NTOK];
  __shared__ int cnt1[CHUNKS][E];
  __shared__ int cnt2[CHUNKS][E];

  const int b = blockIdx.x;
  const int tid = threadIdx.x;
  const int wave = tid >> 6;
  const int lane = tid & 63;
  const unsigned long long lt = (lane == 63) ? 0x7FFFFFFFFFFFFFFFull
                                             : ((1ull << lane) - 1ull);

#pragma unroll
  for (int ci = 0; ci < 2; ++ci) {
    const int c = wave * 2 + ci;
    const int base = c * CHTOK;
    int e1 = i1[b * NTOK + base + lane];
    int e2 = i2r[b * NTOK + base + lane];
    int p1 = 0, p2 = 0, myc1 = 0, myc2 = 0;
    for (int e = 0; e < E; ++e) {
      unsigned long long m1 = __ballot(e1 == e);
      unsigned long long m2 = __ballot(e2 == e);
      if (e1 == e) p1 = __popcll(m1 & lt);
      if (e2 == e) p2 = __popcll(m2 & lt);
      if (lane == e) { myc1 = __popcll(m1); myc2 = __popcll(m2); }
    }
    pos1c[base + lane] = (unsigned char)p1;
    pos2c[base + lane] = (unsigned char)p2;
    cnt1[c][lane] = myc1;
    cnt2[c][lane] = myc2;
  }
  __syncthreads();

  if (tid < E) {
    int run1 = 0, run2 = 0;
#pragma unroll 4
    for (int c = 0; c < CHUNKS; ++c) {
      int v1 = cnt1[c][tid]; cnt1[c][tid] = run1; run1 += v1;
      int v2 = cnt2[c][tid]; cnt2[c][tid] = run2; run2 += v2;
    }
    count1[b * E + tid] = run1;   // pre-capacity top-1 totals (density_1)
  }
  __syncthreads();

  float* combine = out + OUT_TENSOR;
#pragma unroll
  for (int ci = 0; ci < 2; ++ci) {
    const int c = wave * 2 + ci;
    const int base = c * CHTOK;
    const int t = b * NTOK + base + lane;
    int e1 = i1[t];
    int e2 = i2r[t];
    int pp1 = cnt1[c][e1] + (int)pos1c[base + lane];
    if (pp1 < CAP) {
      size_t off = (size_t)t * EC + e1 * CAP + pp1;
      combine[off] = g1[t];
      out[off] = 1.f;
    }
    if (e2 >= 0) {
      int pp2 = cnt2[c][e2] + (int)pos2c[base + lane];
      if (pp2 < CAP) {
        size_t off = (size_t)t * EC + e2 * CAP + pp2;
        combine[off] = g2[t];
        out[off] = 1.f;
      }
    }
  }
}

// ------------- Kernel 3: scalar losses (1 block) -------------
__global__ __launch_bounds__(256) void k_final(const float* __restrict__ zpart,
                                               const float* __restrict__ proxyacc,
                                               const int* __restrict__ count1,
                                               float* __restrict__ out) {
  const int tid = threadIdx.x;
  __shared__ float red[256];
  float zs = 0.f;
  for (int i = tid; i < 1024; i += 256) zs += zpart[i];
  red[tid] = zs;
  __syncthreads();
  for (int s = 128; s > 0; s >>= 1) {
    if (tid < s) red[tid] += red[tid + s];
    __syncthreads();
  }
  float ztot = red[0];
  __syncthreads();
  float bs = 0.f;
  for (int i = tid; i < 512; i += 256) bs += proxyacc[i] * (float)count1[i];
  red[tid] = bs;
  __syncthreads();
  for (int s = 128; s > 0; s >>= 1) {
    if (tid < s) red[tid] += red[tid + s];
    __syncthreads();
  }
  if (tid == 0) {
    out[2 * OUT_TENSOR] = red[0] / 524288.f;      // balance_loss
    out[2 * OUT_TENSOR + 1] = ztot / 16384.f;     // router_z_loss
  }
}

extern "C" void kernel_launch(void* const* d_in, const int* in_sizes, int n_in,
                              void* d_out, int out_size, void* d_ws, size_t ws_size,
                              hipStream_t stream) {
  const float* x = (const float*)d_in[0];
  const float* w = (const float*)d_in[1];
  const float* noise = (const float*)d_in[2];
  float* out = (float*)d_out;

  float* ws = (float*)d_ws;
  int* i1 = (int*)ws;                          // 16384
  int* i2r = i1 + TOKENS;                      // 16384
  float* g1 = (float*)(i2r + TOKENS);          // 16384
  float* g2 = g1 + TOKENS;                     // 16384
  float* proxyacc = g2 + TOKENS;               // 512
  int* count1 = (int*)(proxyacc + 512);        // 512
  float* zpart = (float*)(count1 + 512);       // 1024
  unsigned short* wT = (unsigned short*)(zpart + 1024);   // 65536 ushorts

  k_prep<<<256, 256, 0, stream>>>(w, wT, proxyacc);
  k_gemmgate_fill<<<1024, 256, 0, stream>>>(x, wT, noise, i1, i2r, g1, g2,
                                            proxyacc, zpart, out);
  k_pos_scatter<<<NB, 1024, 0, stream>>>(i1, i2r, g1, g2, count1, out);
  k_final<<<1, 256, 0, stream>>>(zpart, proxyacc, count1, out);
}